// Round 1
// baseline (3438.375 us; speedup 1.0000x reference)
//
#include <hip/hip_runtime.h>
#include <cstdint>

typedef unsigned short bf16u;
typedef __attribute__((ext_vector_type(8))) short short8;
typedef __attribute__((ext_vector_type(4))) float f32x4;

#define SEQ   2048
#define EMB   2048
#define NHEAD 16
#define NKV   4
#define DKH   128
#define HIDN  8192
#define NVOC  32000
#define NLAY  4
#define WIN   1024
#define QKV_N 3072

__device__ __forceinline__ bf16u f2bf(float f) {
  union { float f; uint32_t u; } v; v.f = f;
  uint32_t r = v.u + 0x7FFFu + ((v.u >> 16) & 1u);
  return (bf16u)(r >> 16);
}
__device__ __forceinline__ float bf2f(bf16u b) {
  union { uint32_t u; float f; } v; v.u = ((uint32_t)b) << 16;
  return v.f;
}

// ---------------- embedding ----------------
__global__ __launch_bounds__(256) void embed_kernel(const int* __restrict__ tokens,
                                                    const float* __restrict__ table,
                                                    float* __restrict__ x) {
  int s = blockIdx.x;
  int tok = tokens[s];
  int i0 = threadIdx.x * 8;
  float4 a = {0,0,0,0}, b = {0,0,0,0};
  if (tok != 0) {
    const float* src = table + (size_t)tok * EMB;
    a = *(const float4*)(src + i0);
    b = *(const float4*)(src + i0 + 4);
  }
  *(float4*)(x + (size_t)s * EMB + i0) = a;
  *(float4*)(x + (size_t)s * EMB + i0 + 4) = b;
}

// ---------------- rmsnorm (f32 in -> bf16 out) ----------------
__global__ __launch_bounds__(256) void rmsnorm_kernel(const float* __restrict__ x,
                                                      bf16u* __restrict__ out) {
  int s = blockIdx.x;
  const float* row = x + (size_t)s * EMB;
  int i0 = threadIdx.x * 8;
  float4 a = *(const float4*)(row + i0);
  float4 b = *(const float4*)(row + i0 + 4);
  float ss = a.x*a.x + a.y*a.y + a.z*a.z + a.w*a.w
           + b.x*b.x + b.y*b.y + b.z*b.z + b.w*b.w;
  #pragma unroll
  for (int off = 1; off < 64; off <<= 1) ss += __shfl_xor(ss, off);
  __shared__ float red[4];
  if ((threadIdx.x & 63) == 0) red[threadIdx.x >> 6] = ss;
  __syncthreads();
  float scale = rsqrtf((red[0] + red[1] + red[2] + red[3]) * (1.0f / EMB) + 1e-5f);
  float v[8] = {a.x, a.y, a.z, a.w, b.x, b.y, b.z, b.w};
  short8 o;
  #pragma unroll
  for (int j = 0; j < 8; ++j) o[j] = (short)f2bf(v[j] * scale);
  *(short8*)(out + (size_t)s * EMB + i0) = o;
}

// ---------------- transpose + f32->bf16 convert: in[R][C] -> out[C][R] ----------------
__global__ __launch_bounds__(256) void transp_kernel(const float* __restrict__ in,
                                                     bf16u* __restrict__ out,
                                                     int R, int C) {
  __shared__ float tile[32][33];
  int c0 = blockIdx.x * 32, r0 = blockIdx.y * 32;
  int tx = threadIdx.x & 31, ty = threadIdx.x >> 5;
  #pragma unroll
  for (int i = 0; i < 4; ++i)
    tile[ty + i * 8][tx] = in[(size_t)(r0 + ty + i * 8) * C + c0 + tx];
  __syncthreads();
  #pragma unroll
  for (int i = 0; i < 4; ++i)
    out[(size_t)(c0 + ty + i * 8) * R + r0 + tx] = f2bf(tile[tx][ty + i * 8]);
}

// ---------------- RoPE: qkv_f32[s][3072] -> per-head bf16 [h][s][128] ----------------
__global__ __launch_bounds__(256) void rope_kernel(const float* __restrict__ qkv,
                                                   bf16u* __restrict__ out, int col0) {
  int idx = blockIdx.x * 256 + threadIdx.x;
  int d = idx & 63;
  int s = (idx >> 6) & (SEQ - 1);
  int h = idx >> 17;
  const float* row = qkv + (size_t)s * QKV_N + col0 + h * DKH;
  float ang = (float)s * __powf(10000.0f, -(float)d * (1.0f / 64.0f));
  float si, c;
  sincosf(ang, &si, &c);
  float f0 = row[d], f1 = row[d + 64];
  bf16u* orow = out + ((size_t)h * SEQ + s) * DKH;
  orow[d]      = f2bf(c * f0 - si * f1);
  orow[d + 64] = f2bf(c * f1 + si * f0);
}

__global__ __launch_bounds__(256) void vconv_kernel(const float* __restrict__ qkv,
                                                    bf16u* __restrict__ vout) {
  int idx = blockIdx.x * 256 + threadIdx.x;
  int d = idx & 127;
  int kv = (idx >> 7) & 3;
  int s = idx >> 9;
  vout[((size_t)kv * SEQ + s) * DKH + d] = f2bf(qkv[(size_t)s * QKV_N + 2560 + kv * DKH + d]);
}

// ---------------- swiglu: gu_f32[s][16384] -> h_bf16[s][8192] ----------------
__global__ __launch_bounds__(256) void swiglu_kernel(const float* __restrict__ gu,
                                                     bf16u* __restrict__ h) {
  size_t idx = (size_t)blockIdx.x * 256 + threadIdx.x;
  int s = (int)(idx >> 13);
  int j = (int)(idx & 8191);
  float g = gu[(size_t)s * 16384 + j];
  float u = gu[(size_t)s * 16384 + 8192 + j];
  float sil = g / (1.0f + __expf(-g));
  h[idx] = f2bf(u * sil);
}

// ---------------- GEMM: C[M][N] = A[M][K](bf16) * Bt[N][K](bf16) ----------------
// MODE 0: write bf16; MODE 1: f32 C += ; MODE 2: write f32
template <int MODE>
__global__ __launch_bounds__(256) void gemm_kernel(const bf16u* __restrict__ A,
                                                   const bf16u* __restrict__ Bt,
                                                   void* __restrict__ C,
                                                   int M, int N, int K) {
  __shared__ __align__(16) char lds[(128 * 64 + 128 * 64) * 2];
  char* As = lds;
  char* Bs = lds + 128 * 64 * 2;
  int n0 = blockIdx.x * 128, m0 = blockIdx.y * 128;
  int t = threadIdx.x;
  int wave = t >> 6, lane = t & 63;
  int wm = (wave >> 1) * 64, wn = (wave & 1) * 64;
  int l15 = lane & 15, l4 = lane >> 4;
  f32x4 acc[4][4] = {};

  for (int k0 = 0; k0 < K; k0 += 64) {
    __syncthreads();
    #pragma unroll
    for (int i = 0; i < 4; ++i) {
      int c = t + i * 256;
      int row = c >> 3, cc = c & 7;
      int off = row * 128 + cc * 16;
      off ^= (row & 7) << 4;
      *(short8*)(As + off) = *(const short8*)(A  + (size_t)(m0 + row) * K + k0 + cc * 8);
      *(short8*)(Bs + off) = *(const short8*)(Bt + (size_t)(n0 + row) * K + k0 + cc * 8);
    }
    __syncthreads();
    #pragma unroll
    for (int ks = 0; ks < 2; ++ks) {
      short8 af[4], bf[4];
      #pragma unroll
      for (int i = 0; i < 4; ++i) {
        int rowa = wm + i * 16 + l15;
        int offa = rowa * 128 + ks * 64 + l4 * 16; offa ^= (rowa & 7) << 4;
        af[i] = *(short8*)(As + offa);
        int rowb = wn + i * 16 + l15;
        int offb = rowb * 128 + ks * 64 + l4 * 16; offb ^= (rowb & 7) << 4;
        bf[i] = *(short8*)(Bs + offb);
      }
      #pragma unroll
      for (int i = 0; i < 4; ++i)
        #pragma unroll
        for (int j = 0; j < 4; ++j)
          acc[i][j] = __builtin_amdgcn_mfma_f32_16x16x32_bf16(af[i], bf[j], acc[i][j], 0, 0, 0);
    }
  }

  #pragma unroll
  for (int i = 0; i < 4; ++i)
    #pragma unroll
    for (int j = 0; j < 4; ++j) {
      int col = n0 + wn + j * 16 + l15;
      #pragma unroll
      for (int r = 0; r < 4; ++r) {
        int row = m0 + wm + i * 16 + l4 * 4 + r;
        float v = acc[i][j][r];
        if (MODE == 0) {
          ((bf16u*)C)[(size_t)row * N + col] = f2bf(v);
        } else if (MODE == 1) {
          float* p = (float*)C + (size_t)row * N + col;
          *p += v;
        } else {
          ((float*)C)[(size_t)row * N + col] = v;
        }
      }
    }
}

// ---------------- sliding-window flash attention ----------------
// q_bf[h][s][128], k_bf[kv][s][128], v_bf[kv][s][128] -> attn_bf[s][h*128+d]
__global__ __launch_bounds__(256) void attn_kernel(const bf16u* __restrict__ q_bf,
                                                   const bf16u* __restrict__ k_bf,
                                                   const bf16u* __restrict__ v_bf,
                                                   bf16u* __restrict__ attn_out) {
  int h = blockIdx.y;
  int q0 = blockIdx.x * 64;
  int kvh = h >> 2;
  const bf16u* Kp = k_bf + (size_t)kvh * SEQ * DKH;
  const bf16u* Vp = v_bf + (size_t)kvh * SEQ * DKH;

  __shared__ __align__(16) char  Klds[32 * 128 * 2];   // swizzled [key][dim]
  __shared__ __align__(16) bf16u Vlds[128][40];        // [dim][key] (padded)
  __shared__ __align__(16) bf16u Plds[4][16][40];      // per-wave [qrow][key]

  int t = threadIdx.x, wave = t >> 6, lane = t & 63;
  int l15 = lane & 15, l4 = lane >> 4;
  int qrow0 = q0 + wave * 16;

  short8 qf[4];
  #pragma unroll
  for (int ks = 0; ks < 4; ++ks)
    qf[ks] = *(const short8*)(q_bf + ((size_t)h * SEQ + qrow0 + l15) * DKH + ks * 32 + l4 * 8);

  f32x4 o[8] = {};
  float m[4], lsum[4];
  #pragma unroll
  for (int r = 0; r < 4; ++r) { m[r] = -INFINITY; lsum[r] = 0.0f; }

  int jstart = q0 >= (WIN - 1) ? ((q0 - (WIN - 1)) & ~31) : 0;

  for (int j0 = jstart; j0 < q0 + 64; j0 += 32) {
    __syncthreads();
    // stage K tile (32x128), XOR-swizzled rows
    #pragma unroll
    for (int i = 0; i < 2; ++i) {
      int c = t + i * 256;
      int key = c >> 4, cc = c & 15;
      int off = key * 256 + cc * 16; off ^= (key & 7) << 4;
      *(short8*)(Klds + off) = *(const short8*)(Kp + (size_t)(j0 + key) * DKH + cc * 8);
    }
    // stage V transposed
    {
      int key = t >> 3, d0 = (t & 7) * 16;
      const bf16u* src = Vp + (size_t)(j0 + key) * DKH + d0;
      #pragma unroll
      for (int i = 0; i < 16; ++i) Vlds[d0 + i][key] = src[i];
    }
    __syncthreads();

    // S = Q K^T  (two 16-key column tiles)
    f32x4 sacc[2] = {};
    #pragma unroll
    for (int nt = 0; nt < 2; ++nt) {
      int key = nt * 16 + l15;
      #pragma unroll
      for (int ks = 0; ks < 4; ++ks) {
        int off = key * 256 + ks * 64 + l4 * 16; off ^= (key & 7) << 4;
        short8 kf = *(short8*)(Klds + off);
        sacc[nt] = __builtin_amdgcn_mfma_f32_16x16x32_bf16(qf[ks], kf, sacc[nt], 0, 0, 0);
      }
    }

    // mask + scale
    float sv[2][4];
    #pragma unroll
    for (int nt = 0; nt < 2; ++nt) {
      int jk = j0 + nt * 16 + l15;
      #pragma unroll
      for (int r = 0; r < 4; ++r) {
        int iq = qrow0 + l4 * 4 + r;
        float s = sacc[nt][r] * 0.08838834764831845f;
        bool valid = (jk <= iq) && (iq - jk < WIN);
        sv[nt][r] = valid ? s : -1e9f;
      }
    }

    // online softmax update
    float p[2][4];
    #pragma unroll
    for (int r = 0; r < 4; ++r) {
      float mx = fmaxf(sv[0][r], sv[1][r]);
      #pragma unroll
      for (int off = 1; off < 16; off <<= 1) mx = fmaxf(mx, __shfl_xor(mx, off));
      float mn = fmaxf(m[r], mx);
      float alpha = __expf(m[r] - mn);
      p[0][r] = __expf(sv[0][r] - mn);
      p[1][r] = __expf(sv[1][r] - mn);
      float ps = p[0][r] + p[1][r];
      #pragma unroll
      for (int off = 1; off < 16; off <<= 1) ps += __shfl_xor(ps, off);
      lsum[r] = lsum[r] * alpha + ps;
      m[r] = mn;
      #pragma unroll
      for (int d = 0; d < 8; ++d) o[d][r] *= alpha;
    }

    // write P -> per-wave LDS (bf16), then PV
    #pragma unroll
    for (int nt = 0; nt < 2; ++nt)
      #pragma unroll
      for (int r = 0; r < 4; ++r)
        Plds[wave][l4 * 4 + r][nt * 16 + l15] = f2bf(p[nt][r]);

    short8 pf = *(short8*)(&Plds[wave][l15][l4 * 8]);
    #pragma unroll
    for (int d = 0; d < 8; ++d) {
      short8 vf = *(short8*)(&Vlds[d * 16 + l15][l4 * 8]);
      o[d] = __builtin_amdgcn_mfma_f32_16x16x32_bf16(pf, vf, o[d], 0, 0, 0);
    }
  }

  #pragma unroll
  for (int d = 0; d < 8; ++d)
    #pragma unroll
    for (int r = 0; r < 4; ++r) {
      int row = qrow0 + l4 * 4 + r;
      attn_out[(size_t)row * (NHEAD * DKH) + h * DKH + d * 16 + l15] = f2bf(o[d][r] / lsum[r]);
    }
}

// ---------------- host ----------------
extern "C" void kernel_launch(void* const* d_in, const int* in_sizes, int n_in,
                              void* d_out, int out_size, void* d_ws, size_t ws_size,
                              hipStream_t stream) {
  const int*   tokens  = (const int*)d_in[0];
  const float* table   = (const float*)d_in[1];
  const float* wq      = (const float*)d_in[2];
  const float* wk      = (const float*)d_in[3];
  const float* wv      = (const float*)d_in[4];
  const float* wo      = (const float*)d_in[5];
  const float* w_up    = (const float*)d_in[6];
  const float* w_down  = (const float*)d_in[7];
  const float* w_vocab = (const float*)d_in[8];
  float* out = (float*)d_out;

  char* base = (char*)d_ws;
  size_t o = 0;
  auto alloc = [&](size_t bytes) { size_t r = o; o += (bytes + 255) & ~(size_t)255; return r; };
  size_t o_x     = alloc((size_t)SEQ * EMB * 4);
  size_t o_nbf   = alloc((size_t)SEQ * EMB * 2);
  size_t o_qkvw  = alloc((size_t)QKV_N * EMB * 2);
  size_t o_wot   = alloc((size_t)EMB * EMB * 2);
  size_t o_wupt  = alloc((size_t)2 * HIDN * EMB * 2);
  size_t o_wdnt  = alloc((size_t)EMB * HIDN * 2);
  size_t o_qkvf  = alloc((size_t)SEQ * QKV_N * 4);
  size_t o_qbf   = alloc((size_t)NHEAD * SEQ * DKH * 2);
  size_t o_kbf   = alloc((size_t)NKV * SEQ * DKH * 2);
  size_t o_vbf   = alloc((size_t)NKV * SEQ * DKH * 2);
  size_t o_attn  = alloc((size_t)SEQ * EMB * 2);
  size_t o_guf   = alloc((size_t)SEQ * 2 * HIDN * 4);
  size_t o_hbf   = alloc((size_t)SEQ * HIDN * 2);
  size_t o_wvoct = o_guf;  // alias: vocab weight reuses gu region (dead by then)

  float* x      = (float*)(base + o_x);
  bf16u* n_bf   = (bf16u*)(base + o_nbf);
  bf16u* qkvw_t = (bf16u*)(base + o_qkvw);
  bf16u* wo_t   = (bf16u*)(base + o_wot);
  bf16u* wup_t  = (bf16u*)(base + o_wupt);
  bf16u* wdn_t  = (bf16u*)(base + o_wdnt);
  float* qkv_f  = (float*)(base + o_qkvf);
  bf16u* q_bf   = (bf16u*)(base + o_qbf);
  bf16u* k_bf   = (bf16u*)(base + o_kbf);
  bf16u* v_bf   = (bf16u*)(base + o_vbf);
  bf16u* attn_b = (bf16u*)(base + o_attn);
  float* gu_f   = (float*)(base + o_guf);
  bf16u* h_bf   = (bf16u*)(base + o_hbf);
  bf16u* wvoc_t = (bf16u*)(base + o_wvoct);

  embed_kernel<<<SEQ, 256, 0, stream>>>(tokens, table, x);

  for (int l = 0; l < NLAY; ++l) {
    // weight transposes for this layer
    transp_kernel<<<dim3(EMB / 32, EMB / 32), 256, 0, stream>>>(
        wq + (size_t)l * EMB * EMB, qkvw_t, EMB, EMB);
    transp_kernel<<<dim3(512 / 32, EMB / 32), 256, 0, stream>>>(
        wk + (size_t)l * EMB * 512, qkvw_t + (size_t)2048 * EMB, EMB, 512);
    transp_kernel<<<dim3(512 / 32, EMB / 32), 256, 0, stream>>>(
        wv + (size_t)l * EMB * 512, qkvw_t + (size_t)2560 * EMB, EMB, 512);
    transp_kernel<<<dim3(EMB / 32, EMB / 32), 256, 0, stream>>>(
        wo + (size_t)l * EMB * EMB, wo_t, EMB, EMB);
    transp_kernel<<<dim3(2 * HIDN / 32, EMB / 32), 256, 0, stream>>>(
        w_up + (size_t)l * EMB * 2 * HIDN, wup_t, EMB, 2 * HIDN);
    transp_kernel<<<dim3(EMB / 32, HIDN / 32), 256, 0, stream>>>(
        w_down + (size_t)l * HIDN * EMB, wdn_t, HIDN, EMB);

    rmsnorm_kernel<<<SEQ, 256, 0, stream>>>(x, n_bf);
    gemm_kernel<2><<<dim3(QKV_N / 128, SEQ / 128), 256, 0, stream>>>(
        n_bf, qkvw_t, qkv_f, SEQ, QKV_N, EMB);

    rope_kernel<<<NHEAD * SEQ * 64 / 256, 256, 0, stream>>>(qkv_f, q_bf, 0);
    rope_kernel<<<NKV * SEQ * 64 / 256, 256, 0, stream>>>(qkv_f, k_bf, 2048);
    vconv_kernel<<<NKV * SEQ * 128 / 256, 256, 0, stream>>>(qkv_f, v_bf);

    attn_kernel<<<dim3(SEQ / 64, NHEAD), 256, 0, stream>>>(q_bf, k_bf, v_bf, attn_b);

    gemm_kernel<1><<<dim3(EMB / 128, SEQ / 128), 256, 0, stream>>>(
        attn_b, wo_t, x, SEQ, EMB, EMB);

    rmsnorm_kernel<<<SEQ, 256, 0, stream>>>(x, n_bf);
    gemm_kernel<2><<<dim3(2 * HIDN / 128, SEQ / 128), 256, 0, stream>>>(
        n_bf, wup_t, gu_f, SEQ, 2 * HIDN, EMB);
    swiglu_kernel<<<SEQ * HIDN / 256, 256, 0, stream>>>(gu_f, h_bf);
    gemm_kernel<1><<<dim3(EMB / 128, SEQ / 128), 256, 0, stream>>>(
        h_bf, wdn_t, x, SEQ, EMB, HIDN);
  }

  // final norm + vocab projection (vocab weight converted into gu region, now dead)
  transp_kernel<<<dim3(NVOC / 32, EMB / 32), 256, 0, stream>>>(w_vocab, wvoc_t, EMB, NVOC);
  rmsnorm_kernel<<<SEQ, 256, 0, stream>>>(x, n_bf);
  gemm_kernel<2><<<dim3(NVOC / 128, SEQ / 128), 256, 0, stream>>>(
      n_bf, wvoc_t, out, SEQ, NVOC, EMB);
}

// Round 2
// 3234.709 us; speedup vs baseline: 1.0630x; 1.0630x over previous
//
#include <hip/hip_runtime.h>
#include <cstdint>

typedef unsigned short bf16u;
typedef __attribute__((ext_vector_type(8))) short short8;
typedef __attribute__((ext_vector_type(4))) float f32x4;

#define SEQ   2048
#define EMB   2048
#define NHEAD 16
#define NKV   4
#define DKH   128
#define HIDN  8192
#define NVOC  32000
#define NLAY  4
#define WIN   1024
#define QKV_N 3072

__device__ __forceinline__ bf16u f2bf(float f) {
  union { float f; uint32_t u; } v; v.f = f;
  uint32_t r = v.u + 0x7FFFu + ((v.u >> 16) & 1u);
  return (bf16u)(r >> 16);
}
__device__ __forceinline__ float bf2f(bf16u b) {
  union { uint32_t u; float f; } v; v.u = ((uint32_t)b) << 16;
  return v.f;
}

__device__ __forceinline__ void gl2lds16(const void* g, void* l) {
  __builtin_amdgcn_global_load_lds(
      (const __attribute__((address_space(1))) void*)g,
      (__attribute__((address_space(3))) void*)l, 16, 0, 0);
}

// ---------------- embedding ----------------
__global__ __launch_bounds__(256) void embed_kernel(const int* __restrict__ tokens,
                                                    const float* __restrict__ table,
                                                    float* __restrict__ x) {
  int s = blockIdx.x;
  int tok = tokens[s];
  int i0 = threadIdx.x * 8;
  float4 a = {0,0,0,0}, b = {0,0,0,0};
  if (tok != 0) {
    const float* src = table + (size_t)tok * EMB;
    a = *(const float4*)(src + i0);
    b = *(const float4*)(src + i0 + 4);
  }
  *(float4*)(x + (size_t)s * EMB + i0) = a;
  *(float4*)(x + (size_t)s * EMB + i0 + 4) = b;
}

// ---------------- rmsnorm (f32 in -> bf16 out) ----------------
__global__ __launch_bounds__(256) void rmsnorm_kernel(const float* __restrict__ x,
                                                      bf16u* __restrict__ out) {
  int s = blockIdx.x;
  const float* row = x + (size_t)s * EMB;
  int i0 = threadIdx.x * 8;
  float4 a = *(const float4*)(row + i0);
  float4 b = *(const float4*)(row + i0 + 4);
  float ss = a.x*a.x + a.y*a.y + a.z*a.z + a.w*a.w
           + b.x*b.x + b.y*b.y + b.z*b.z + b.w*b.w;
  #pragma unroll
  for (int off = 1; off < 64; off <<= 1) ss += __shfl_xor(ss, off);
  __shared__ float red[4];
  if ((threadIdx.x & 63) == 0) red[threadIdx.x >> 6] = ss;
  __syncthreads();
  float scale = rsqrtf((red[0] + red[1] + red[2] + red[3]) * (1.0f / EMB) + 1e-5f);
  float v[8] = {a.x, a.y, a.z, a.w, b.x, b.y, b.z, b.w};
  short8 o;
  #pragma unroll
  for (int j = 0; j < 8; ++j) o[j] = (short)f2bf(v[j] * scale);
  *(short8*)(out + (size_t)s * EMB + i0) = o;
}

// ---------------- transpose + f32->bf16 convert: in[R][C] -> out[C][R] ----------------
__global__ __launch_bounds__(256) void transp_kernel(const float* __restrict__ in,
                                                     bf16u* __restrict__ out,
                                                     int R, int C) {
  __shared__ float tile[32][33];
  int c0 = blockIdx.x * 32, r0 = blockIdx.y * 32;
  int tx = threadIdx.x & 31, ty = threadIdx.x >> 5;
  #pragma unroll
  for (int i = 0; i < 4; ++i)
    tile[ty + i * 8][tx] = in[(size_t)(r0 + ty + i * 8) * C + c0 + tx];
  __syncthreads();
  #pragma unroll
  for (int i = 0; i < 4; ++i)
    out[(size_t)(c0 + ty + i * 8) * R + r0 + tx] = f2bf(tile[tx][ty + i * 8]);
}

// ---------------- RoPE: qkv_f32[s][3072] -> per-head bf16 [h][s][128] ----------------
__global__ __launch_bounds__(256) void rope_kernel(const float* __restrict__ qkv,
                                                   bf16u* __restrict__ out, int col0) {
  int idx = blockIdx.x * 256 + threadIdx.x;
  int d = idx & 63;
  int s = (idx >> 6) & (SEQ - 1);
  int h = idx >> 17;
  const float* row = qkv + (size_t)s * QKV_N + col0 + h * DKH;
  float ang = (float)s * __powf(10000.0f, -(float)d * (1.0f / 64.0f));
  float si, c;
  sincosf(ang, &si, &c);
  float f0 = row[d], f1 = row[d + 64];
  bf16u* orow = out + ((size_t)h * SEQ + s) * DKH;
  orow[d]      = f2bf(c * f0 - si * f1);
  orow[d + 64] = f2bf(c * f1 + si * f0);
}

__global__ __launch_bounds__(256) void vconv_kernel(const float* __restrict__ qkv,
                                                    bf16u* __restrict__ vout) {
  int idx = blockIdx.x * 256 + threadIdx.x;
  int d = idx & 127;
  int kv = (idx >> 7) & 3;
  int s = idx >> 9;
  vout[((size_t)kv * SEQ + s) * DKH + d] = f2bf(qkv[(size_t)s * QKV_N + 2560 + kv * DKH + d]);
}

// ---------------- swiglu: gu_f32[s][16384] -> h_bf16[s][8192] ----------------
__global__ __launch_bounds__(256) void swiglu_kernel(const float* __restrict__ gu,
                                                     bf16u* __restrict__ h) {
  size_t idx = (size_t)blockIdx.x * 256 + threadIdx.x;
  int s = (int)(idx >> 13);
  int j = (int)(idx & 8191);
  float g = gu[(size_t)s * 16384 + j];
  float u = gu[(size_t)s * 16384 + 8192 + j];
  float sil = g / (1.0f + __expf(-g));
  h[idx] = f2bf(u * sil);
}

// ---------------- GEMM (m97 structure): C[M][N] = A[M][K](bf16) * Bt[N][K](bf16)
// BK=32, global_load_lds width-16 staging, linear LDS, 2-phase double buffer,
// XCD-bijective block swizzle with by-fastest decomposition (B-panel L2 reuse).
// MODE 0: write bf16; MODE 1: f32 C += ; MODE 2: write f32
template <int MODE>
__global__ __launch_bounds__(256) void gemm_kernel(const bf16u* __restrict__ A,
                                                   const bf16u* __restrict__ Bt,
                                                   void* __restrict__ C,
                                                   int M, int N, int K) {
  // lds[buf][A/B][128 rows][32 cols] bf16, linear
  __shared__ __align__(16) char lds[2][2][8192];

  int nx = gridDim.x, ny = gridDim.y;
  int nwg = nx * ny;
  int orig = blockIdx.y * nx + blockIdx.x;
  // bijective XCD chunking (m204)
  int q = nwg >> 3, r = nwg & 7;
  int xcd = orig & 7, loc = orig >> 3;
  int id = (xcd < r ? xcd * (q + 1) : r * (q + 1) + (xcd - r) * q) + loc;
  // by fastest: consecutive ids share bx -> B panel L2 reuse within XCD
  int bx = id / ny, by = id - bx * ny;
  int n0 = bx * 128, m0 = by * 128;

  int t = threadIdx.x;
  int w = t >> 6, l = t & 63;
  int wm = (w >> 1) * 64, wn = (w & 1) * 64;
  int l15 = l & 15, l4 = l >> 4;

  // staging geometry: issue i covers rows [i*64 + w*16, +16), lane l -> row +l/4, kcol (l&3)*8
  int srow = w * 16 + (l >> 2);
  int scol = (l & 3) * 8;

  f32x4 acc[4][4] = {};

  auto stage = [&](int buf, int k0) {
    #pragma unroll
    for (int i = 0; i < 2; ++i) {
      gl2lds16(A  + (size_t)(m0 + i * 64 + srow) * K + k0 + scol,
               &lds[buf][0][i * 4096 + w * 1024]);
      gl2lds16(Bt + (size_t)(n0 + i * 64 + srow) * K + k0 + scol,
               &lds[buf][1][i * 4096 + w * 1024]);
    }
  };

  auto compute = [&](int buf) {
    short8 af[4], bfr[4];
    #pragma unroll
    for (int i = 0; i < 4; ++i) {
      af[i]  = *(const short8*)(&lds[buf][0][((wm + i * 16 + l15) * 32 + l4 * 8) * 2]);
      bfr[i] = *(const short8*)(&lds[buf][1][((wn + i * 16 + l15) * 32 + l4 * 8) * 2]);
    }
    #pragma unroll
    for (int i = 0; i < 4; ++i)
      #pragma unroll
      for (int j = 0; j < 4; ++j)
        acc[i][j] = __builtin_amdgcn_mfma_f32_16x16x32_bf16(af[i], bfr[j], acc[i][j], 0, 0, 0);
  };

  int nt = K >> 5;
  int cur = 0;
  stage(0, 0);
  __syncthreads();  // drains vmcnt(0)
  for (int tt = 0; tt < nt; ++tt) {
    if (tt + 1 < nt) stage(cur ^ 1, (tt + 1) * 32);
    compute(cur);
    __syncthreads();  // drains staged loads; protects buf reuse
    cur ^= 1;
  }

  #pragma unroll
  for (int i = 0; i < 4; ++i)
    #pragma unroll
    for (int j = 0; j < 4; ++j) {
      int col = n0 + wn + j * 16 + l15;
      #pragma unroll
      for (int rr = 0; rr < 4; ++rr) {
        int row = m0 + wm + i * 16 + l4 * 4 + rr;
        float v = acc[i][j][rr];
        if (MODE == 0) {
          ((bf16u*)C)[(size_t)row * N + col] = f2bf(v);
        } else if (MODE == 1) {
          float* p = (float*)C + (size_t)row * N + col;
          *p += v;
        } else {
          ((float*)C)[(size_t)row * N + col] = v;
        }
      }
    }
}

// ---------------- sliding-window flash attention ----------------
__global__ __launch_bounds__(256) void attn_kernel(const bf16u* __restrict__ q_bf,
                                                   const bf16u* __restrict__ k_bf,
                                                   const bf16u* __restrict__ v_bf,
                                                   bf16u* __restrict__ attn_out) {
  int h = blockIdx.y;
  int q0 = blockIdx.x * 64;
  int kvh = h >> 2;
  const bf16u* Kp = k_bf + (size_t)kvh * SEQ * DKH;
  const bf16u* Vp = v_bf + (size_t)kvh * SEQ * DKH;

  __shared__ __align__(16) char  Klds[32 * 128 * 2];   // swizzled [key][dim]
  __shared__ __align__(16) bf16u Vlds[128][40];        // [dim][key] (padded)
  __shared__ __align__(16) bf16u Plds[4][16][40];      // per-wave [qrow][key]

  int t = threadIdx.x, wave = t >> 6, lane = t & 63;
  int l15 = lane & 15, l4 = lane >> 4;
  int qrow0 = q0 + wave * 16;

  short8 qf[4];
  #pragma unroll
  for (int ks = 0; ks < 4; ++ks)
    qf[ks] = *(const short8*)(q_bf + ((size_t)h * SEQ + qrow0 + l15) * DKH + ks * 32 + l4 * 8);

  f32x4 o[8] = {};
  float m[4], lsum[4];
  #pragma unroll
  for (int r = 0; r < 4; ++r) { m[r] = -INFINITY; lsum[r] = 0.0f; }

  int jstart = q0 >= (WIN - 1) ? ((q0 - (WIN - 1)) & ~31) : 0;

  for (int j0 = jstart; j0 < q0 + 64; j0 += 32) {
    __syncthreads();
    #pragma unroll
    for (int i = 0; i < 2; ++i) {
      int c = t + i * 256;
      int key = c >> 4, cc = c & 15;
      int off = key * 256 + cc * 16; off ^= (key & 7) << 4;
      *(short8*)(Klds + off) = *(const short8*)(Kp + (size_t)(j0 + key) * DKH + cc * 8);
    }
    {
      int key = t >> 3, d0 = (t & 7) * 16;
      const bf16u* src = Vp + (size_t)(j0 + key) * DKH + d0;
      #pragma unroll
      for (int i = 0; i < 16; ++i) Vlds[d0 + i][key] = src[i];
    }
    __syncthreads();

    f32x4 sacc[2] = {};
    #pragma unroll
    for (int nt = 0; nt < 2; ++nt) {
      int key = nt * 16 + l15;
      #pragma unroll
      for (int ks = 0; ks < 4; ++ks) {
        int off = key * 256 + ks * 64 + l4 * 16; off ^= (key & 7) << 4;
        short8 kf = *(short8*)(Klds + off);
        sacc[nt] = __builtin_amdgcn_mfma_f32_16x16x32_bf16(qf[ks], kf, sacc[nt], 0, 0, 0);
      }
    }

    float sv[2][4];
    #pragma unroll
    for (int nt = 0; nt < 2; ++nt) {
      int jk = j0 + nt * 16 + l15;
      #pragma unroll
      for (int r = 0; r < 4; ++r) {
        int iq = qrow0 + l4 * 4 + r;
        float s = sacc[nt][r] * 0.08838834764831845f;
        bool valid = (jk <= iq) && (iq - jk < WIN);
        sv[nt][r] = valid ? s : -1e9f;
      }
    }

    float p[2][4];
    #pragma unroll
    for (int r = 0; r < 4; ++r) {
      float mx = fmaxf(sv[0][r], sv[1][r]);
      #pragma unroll
      for (int off = 1; off < 16; off <<= 1) mx = fmaxf(mx, __shfl_xor(mx, off));
      float mn = fmaxf(m[r], mx);
      float alpha = __expf(m[r] - mn);
      p[0][r] = __expf(sv[0][r] - mn);
      p[1][r] = __expf(sv[1][r] - mn);
      float ps = p[0][r] + p[1][r];
      #pragma unroll
      for (int off = 1; off < 16; off <<= 1) ps += __shfl_xor(ps, off);
      lsum[r] = lsum[r] * alpha + ps;
      m[r] = mn;
      #pragma unroll
      for (int d = 0; d < 8; ++d) o[d][r] *= alpha;
    }

    #pragma unroll
    for (int nt = 0; nt < 2; ++nt)
      #pragma unroll
      for (int r = 0; r < 4; ++r)
        Plds[wave][l4 * 4 + r][nt * 16 + l15] = f2bf(p[nt][r]);

    short8 pf = *(short8*)(&Plds[wave][l15][l4 * 8]);
    #pragma unroll
    for (int d = 0; d < 8; ++d) {
      short8 vf = *(short8*)(&Vlds[d * 16 + l15][l4 * 8]);
      o[d] = __builtin_amdgcn_mfma_f32_16x16x32_bf16(pf, vf, o[d], 0, 0, 0);
    }
  }

  #pragma unroll
  for (int d = 0; d < 8; ++d)
    #pragma unroll
    for (int r = 0; r < 4; ++r) {
      int row = qrow0 + l4 * 4 + r;
      attn_out[(size_t)row * (NHEAD * DKH) + h * DKH + d * 16 + l15] = f2bf(o[d][r] / lsum[r]);
    }
}

// ---------------- host ----------------
extern "C" void kernel_launch(void* const* d_in, const int* in_sizes, int n_in,
                              void* d_out, int out_size, void* d_ws, size_t ws_size,
                              hipStream_t stream) {
  const int*   tokens  = (const int*)d_in[0];
  const float* table   = (const float*)d_in[1];
  const float* wq      = (const float*)d_in[2];
  const float* wk      = (const float*)d_in[3];
  const float* wv      = (const float*)d_in[4];
  const float* wo      = (const float*)d_in[5];
  const float* w_up    = (const float*)d_in[6];
  const float* w_down  = (const float*)d_in[7];
  const float* w_vocab = (const float*)d_in[8];
  float* out = (float*)d_out;

  char* base = (char*)d_ws;
  size_t o = 0;
  auto alloc = [&](size_t bytes) { size_t r = o; o += (bytes + 255) & ~(size_t)255; return r; };
  size_t o_x     = alloc((size_t)SEQ * EMB * 4);
  size_t o_nbf   = alloc((size_t)SEQ * EMB * 2);
  size_t o_qkvw  = alloc((size_t)QKV_N * EMB * 2);
  size_t o_wot   = alloc((size_t)EMB * EMB * 2);
  size_t o_wupt  = alloc((size_t)2 * HIDN * EMB * 2);
  size_t o_wdnt  = alloc((size_t)EMB * HIDN * 2);
  size_t o_qkvf  = alloc((size_t)SEQ * QKV_N * 4);
  size_t o_qbf   = alloc((size_t)NHEAD * SEQ * DKH * 2);
  size_t o_kbf   = alloc((size_t)NKV * SEQ * DKH * 2);
  size_t o_vbf   = alloc((size_t)NKV * SEQ * DKH * 2);
  size_t o_attn  = alloc((size_t)SEQ * EMB * 2);
  size_t o_guf   = alloc((size_t)SEQ * 2 * HIDN * 4);
  size_t o_hbf   = alloc((size_t)SEQ * HIDN * 2);
  size_t o_wvoct = o_guf;  // alias: vocab weight reuses gu region (dead by then)

  float* x      = (float*)(base + o_x);
  bf16u* n_bf   = (bf16u*)(base + o_nbf);
  bf16u* qkvw_t = (bf16u*)(base + o_qkvw);
  bf16u* wo_t   = (bf16u*)(base + o_wot);
  bf16u* wup_t  = (bf16u*)(base + o_wupt);
  bf16u* wdn_t  = (bf16u*)(base + o_wdnt);
  float* qkv_f  = (float*)(base + o_qkvf);
  bf16u* q_bf   = (bf16u*)(base + o_qbf);
  bf16u* k_bf   = (bf16u*)(base + o_kbf);
  bf16u* v_bf   = (bf16u*)(base + o_vbf);
  bf16u* attn_b = (bf16u*)(base + o_attn);
  float* gu_f   = (float*)(base + o_guf);
  bf16u* h_bf   = (bf16u*)(base + o_hbf);
  bf16u* wvoc_t = (bf16u*)(base + o_wvoct);

  embed_kernel<<<SEQ, 256, 0, stream>>>(tokens, table, x);

  for (int l = 0; l < NLAY; ++l) {
    transp_kernel<<<dim3(EMB / 32, EMB / 32), 256, 0, stream>>>(
        wq + (size_t)l * EMB * EMB, qkvw_t, EMB, EMB);
    transp_kernel<<<dim3(512 / 32, EMB / 32), 256, 0, stream>>>(
        wk + (size_t)l * EMB * 512, qkvw_t + (size_t)2048 * EMB, EMB, 512);
    transp_kernel<<<dim3(512 / 32, EMB / 32), 256, 0, stream>>>(
        wv + (size_t)l * EMB * 512, qkvw_t + (size_t)2560 * EMB, EMB, 512);
    transp_kernel<<<dim3(EMB / 32, EMB / 32), 256, 0, stream>>>(
        wo + (size_t)l * EMB * EMB, wo_t, EMB, EMB);
    transp_kernel<<<dim3(2 * HIDN / 32, EMB / 32), 256, 0, stream>>>(
        w_up + (size_t)l * EMB * 2 * HIDN, wup_t, EMB, 2 * HIDN);
    transp_kernel<<<dim3(EMB / 32, HIDN / 32), 256, 0, stream>>>(
        w_down + (size_t)l * HIDN * EMB, wdn_t, HIDN, EMB);

    rmsnorm_kernel<<<SEQ, 256, 0, stream>>>(x, n_bf);
    gemm_kernel<2><<<dim3(QKV_N / 128, SEQ / 128), 256, 0, stream>>>(
        n_bf, qkvw_t, qkv_f, SEQ, QKV_N, EMB);

    rope_kernel<<<NHEAD * SEQ * 64 / 256, 256, 0, stream>>>(qkv_f, q_bf, 0);
    rope_kernel<<<NKV * SEQ * 64 / 256, 256, 0, stream>>>(qkv_f, k_bf, 2048);
    vconv_kernel<<<NKV * SEQ * 128 / 256, 256, 0, stream>>>(qkv_f, v_bf);

    attn_kernel<<<dim3(SEQ / 64, NHEAD), 256, 0, stream>>>(q_bf, k_bf, v_bf, attn_b);

    gemm_kernel<1><<<dim3(EMB / 128, SEQ / 128), 256, 0, stream>>>(
        attn_b, wo_t, x, SEQ, EMB, EMB);

    rmsnorm_kernel<<<SEQ, 256, 0, stream>>>(x, n_bf);
    gemm_kernel<2><<<dim3(2 * HIDN / 128, SEQ / 128), 256, 0, stream>>>(
        n_bf, wup_t, gu_f, SEQ, 2 * HIDN, EMB);
    swiglu_kernel<<<SEQ * HIDN / 256, 256, 0, stream>>>(gu_f, h_bf);
    gemm_kernel<1><<<dim3(EMB / 128, SEQ / 128), 256, 0, stream>>>(
        h_bf, wdn_t, x, SEQ, EMB, HIDN);
  }

  transp_kernel<<<dim3(NVOC / 32, EMB / 32), 256, 0, stream>>>(w_vocab, wvoc_t, EMB, NVOC);
  rmsnorm_kernel<<<SEQ, 256, 0, stream>>>(x, n_bf);
  gemm_kernel<2><<<dim3(NVOC / 128, SEQ / 128), 256, 0, stream>>>(
      n_bf, wvoc_t, out, SEQ, NVOC, EMB);
}